// Round 1
// baseline (230.279 us; speedup 1.0000x reference)
//
#include <hip/hip_runtime.h>

#define E_TOT 500000
#define NBLK ((E_TOT + 63) / 64)

typedef __attribute__((ext_vector_type(8))) short short8;
typedef __attribute__((ext_vector_type(4))) float f32x4;

__device__ __forceinline__ unsigned short f2bf(float f) {
  union { float f; unsigned u; } x; x.f = f;
  unsigned r = x.u + 0x7fffu + ((x.u >> 16) & 1u);
  return (unsigned short)(r >> 16);
}

__device__ __forceinline__ void gl_lds16(const void* g, void* l) {
  __builtin_amdgcn_global_load_lds(
      (const __attribute__((address_space(1))) void*)g,
      (__attribute__((address_space(3))) void*)l, 16, 0, 0);
}

// w1 (f32 [256][512]) -> w1r (bf16, layout [kb=0..63][n=0..255][j=0..7])
__global__ void k_repack_w1(const float* __restrict__ w1,
                            unsigned short* __restrict__ w1r) {
  int o = blockIdx.x * 256 + threadIdx.x;  // 131072 total
  int kb = o >> 11;
  int n = (o >> 3) & 255;
  int j = o & 7;
  w1r[o] = f2bf(w1[n * 512 + kb * 8 + j]);
}

__global__ __launch_bounds__(512, 4) void k_decoder(
    const float* __restrict__ zsrc, const float* __restrict__ zdst,
    const int* __restrict__ eli, const unsigned short* __restrict__ w1r,
    const float* __restrict__ b1, const float* __restrict__ w2,
    const float* __restrict__ b2, float* __restrict__ out) {
  // A: [kblk][edge][8] bf16 (8 KB)   B: [kblk][n][8] bf16 (32 KB)
  __shared__ unsigned short A_lds[8][64][8];
  __shared__ unsigned short B_lds[8][256][8];
  __shared__ float partial[8][64];  // 2 KB

  const unsigned tid = threadIdx.x;
  const unsigned l = tid & 63u;
  const unsigned w = tid >> 6;    // wave 0..7
  const unsigned l15 = l & 15u;
  const unsigned lg = l >> 4;     // 0..3

  const long e0 = (long)blockIdx.x * 64;

  // --- staging assignment: lane stages edge eloc, k-slice koff..koff+7 ---
  const unsigned eloc = (w & 3u) * 16u + l15;       // 0..63
  long e = e0 + eloc;
  long eS = (e < E_TOT) ? e : (long)(E_TOT - 1);
  const int nrow = eli[eS];
  const int ncol = eli[E_TOT + eS];
  const float* srcRow = zsrc + (long)nrow * 256;
  const float* dstRow = zdst + (long)ncol * 256;
  const unsigned koff = (w >> 2) * 32u + lg * 8u;   // {0,8,...,56}

  f32x4 acc[4][2];
#pragma unroll
  for (int mf = 0; mf < 4; ++mf)
#pragma unroll
    for (int nf = 0; nf < 2; ++nf)
      acc[mf][nf] = (f32x4){0.f, 0.f, 0.f, 0.f};

  // prologue: prefetch A for chunk 0 (chunk 0 is src half, k base 0)
  f32x4 fa0 = ((const f32x4*)(srcRow + koff))[0];
  f32x4 fa1 = ((const f32x4*)(srcRow + koff))[1];

  for (int c = 0; c < 8; ++c) {
    __syncthreads();  // previous compute done -> LDS writable

    // A(c): cvt regs -> bf16, one ds_write_b128 per lane
    short8 sa;
    sa[0] = (short)f2bf(fa0.x); sa[1] = (short)f2bf(fa0.y);
    sa[2] = (short)f2bf(fa0.z); sa[3] = (short)f2bf(fa0.w);
    sa[4] = (short)f2bf(fa1.x); sa[5] = (short)f2bf(fa1.y);
    sa[6] = (short)f2bf(fa1.z); sa[7] = (short)f2bf(fa1.w);
    *(short8*)&A_lds[koff >> 3][eloc][0] = sa;

    // B(c): 32 KB linear, 4 x global_load_lds(16B) per wave
    const unsigned short* bsrc = w1r + (unsigned)c * 16384u;
    unsigned short* bdst = (unsigned short*)B_lds;
#pragma unroll
    for (int q = 0; q < 4; ++q) {
      unsigned off = (w * 4u + (unsigned)q) * 512u;
      gl_lds16(bsrc + off + l * 8u, bdst + off);
    }

    __syncthreads();  // staging visible (vmcnt/lgkmcnt drained at barrier)

    // prefetch A(c+1): latency hides under compute(c)
    if (c < 7) {
      int cn = c + 1;
      const float* half = (cn < 4) ? srcRow : dstRow;
      const float* g = half + (unsigned)(cn & 3) * 64u + koff;
      fa0 = ((const f32x4*)g)[0];
      fa1 = ((const f32x4*)g)[1];
    }

    // compute chunk c: 2 k-steps x (4 mf x 2 nf) MFMAs
#pragma unroll
    for (int ks = 0; ks < 2; ++ks) {
      short8 bfr0 = *(const short8*)&B_lds[ks * 4 + lg][w * 32u + l15][0];
      short8 bfr1 = *(const short8*)&B_lds[ks * 4 + lg][w * 32u + 16u + l15][0];
#pragma unroll
      for (int mf = 0; mf < 4; ++mf) {
        short8 afr = *(const short8*)&A_lds[ks * 4 + lg][mf * 16 + l15][0];
        acc[mf][0] =
            __builtin_amdgcn_mfma_f32_16x16x32_bf16(afr, bfr0, acc[mf][0], 0, 0, 0);
        acc[mf][1] =
            __builtin_amdgcn_mfma_f32_16x16x32_bf16(afr, bfr1, acc[mf][1], 0, 0, 0);
      }
    }
  }

  // ---- epilogue: h = relu(acc + b1); p = h . w2 ; reduce; sigmoid ----
  float b1v[2], w2v[2];
#pragma unroll
  for (int nf = 0; nf < 2; ++nf) {
    unsigned n = w * 32u + (unsigned)nf * 16u + l15;
    b1v[nf] = b1[n];
    w2v[nf] = w2[n];
  }
#pragma unroll
  for (int mf = 0; mf < 4; ++mf) {
#pragma unroll
    for (int r = 0; r < 4; ++r) {
      float p = 0.f;
#pragma unroll
      for (int nf = 0; nf < 2; ++nf) {
        float h = acc[mf][nf][r] + b1v[nf];
        h = fmaxf(h, 0.f);
        p = fmaf(h, w2v[nf], p);
      }
      // reduce across the 16 lanes (columns) of this fragment row
      p += __shfl_xor(p, 1);
      p += __shfl_xor(p, 2);
      p += __shfl_xor(p, 4);
      p += __shfl_xor(p, 8);
      if (l15 == 0) partial[w][mf * 16 + (int)lg * 4 + r] = p;
    }
  }
  __syncthreads();
  if (tid < 64) {
    long eo = e0 + (long)tid;
    if (eo < E_TOT) {
      float s = b2[0];
#pragma unroll
      for (int ww = 0; ww < 8; ++ww) s += partial[ww][tid];
      out[eo] = 1.f / (1.f + __expf(-s));
    }
  }
}

extern "C" void kernel_launch(void* const* d_in, const int* in_sizes, int n_in,
                              void* d_out, int out_size, void* d_ws,
                              size_t ws_size, hipStream_t stream) {
  const float* zsrc = (const float*)d_in[0];
  const float* zdst = (const float*)d_in[1];
  const int* eli = (const int*)d_in[2];
  const float* w1 = (const float*)d_in[3];
  const float* b1 = (const float*)d_in[4];
  const float* w2 = (const float*)d_in[5];
  const float* b2 = (const float*)d_in[6];
  float* out = (float*)d_out;
  unsigned short* w1r = (unsigned short*)d_ws;  // 256 KB

  k_repack_w1<<<512, 256, 0, stream>>>(w1, w1r);
  k_decoder<<<NBLK, 512, 0, stream>>>(zsrc, zdst, eli, w1r, b1, w2, b2, out);
}